// Round 1
// baseline (507.460 us; speedup 1.0000x reference)
//
#include <hip/hip_runtime.h>
#include <math.h>

#define B_ 64
#define N_ 512
#define NOUT_ 64
#define R_ (B_*N_)            // 32768 rows total
#define INV_S 0.9995003746877732f   // 1/sqrt(1+1e-3)

// ---------------------------------------------------------------------------
// Kernel 1: embeddings + assemble x0 (33 features, padded to 36 with zeros,
// stored with row stride 64), extract mask.
// x0 channels: [e1(2), e2(2), e3(2), xx[...,0:27]] ; coords for layer0 are
// channels 31,32 (= xx ch 25,26).
// ---------------------------------------------------------------------------
__global__ __launch_bounds__(256) void build_x0(
    const float* __restrict__ xx, const float* __restrict__ emb1,
    const float* __restrict__ emb2, const float* __restrict__ emb3,
    float* __restrict__ x0, float* __restrict__ maskb)
{
  int r = blockIdx.x*256 + threadIdx.x;   // 0..32767
  const float* row = xx + (size_t)r*30;
  float v[30];
#pragma unroll
  for (int i=0;i<30;i++) v[i] = row[i];
  int i1 = (int)fabsf(v[27]);
  int i2 = (int)fabsf(v[28]);
  int i3 = (int)fabsf(v[29]);
  float* o = x0 + (size_t)r*64;
  o[0]=emb1[i1*2+0]; o[1]=emb1[i1*2+1];
  o[2]=emb2[i2*2+0]; o[3]=emb2[i2*2+1];
  o[4]=emb3[i3*2+0]; o[5]=emb3[i3*2+1];
#pragma unroll
  for (int i=0;i<27;i++) o[6+i] = v[i];
  o[33]=0.f; o[34]=0.f; o[35]=0.f;       // pad so K=33 GEMM can run K=36
  maskb[r] = v[0];
}

// ---------------------------------------------------------------------------
// Kernel 2: pairwise-distance partial sums.
// grid (N/64, 4 i-chunks, B), block 64. Block (jx,c,b): for its 64 j's,
// sums w=exp(-10*dist) and dist*w over i in [c*128, c*128+128).
// Writes Sp[c][r], Tp[c][r] (no init needed — each slot written once).
// ---------------------------------------------------------------------------
__global__ __launch_bounds__(64) void dist_partial(
    const float* __restrict__ xbuf, int coff, int ndim,
    float* __restrict__ Sp, float* __restrict__ Tp)
{
  __shared__ float4 cl[128];
  int jx = blockIdx.x, c = blockIdx.y, b = blockIdx.z;
  int tid = threadIdx.x;
  for (int i = tid; i < 128; i += 64){
    int r = b*N_ + c*128 + i;
    float4 cv;
    cv.x = xbuf[(size_t)r*64 + coff + 0];
    cv.y = xbuf[(size_t)r*64 + coff + 1];
    cv.z = (ndim > 2) ? xbuf[(size_t)r*64 + coff + 2] : 0.f;
    cv.w = (ndim > 2) ? xbuf[(size_t)r*64 + coff + 3] : 0.f;
    cl[i] = cv;
  }
  __syncthreads();
  int rj = b*N_ + jx*64 + tid;
  float4 cj;
  cj.x = xbuf[(size_t)rj*64 + coff + 0];
  cj.y = xbuf[(size_t)rj*64 + coff + 1];
  cj.z = (ndim > 2) ? xbuf[(size_t)rj*64 + coff + 2] : 0.f;
  cj.w = (ndim > 2) ? xbuf[(size_t)rj*64 + coff + 3] : 0.f;
  float Ss = 0.f, Ts = 0.f;
#pragma unroll 4
  for (int i=0;i<128;i++){
    float4 ci = cl[i];
    float d0 = cj.x-ci.x, d1 = cj.y-ci.y, d2 = cj.z-ci.z, d3 = cj.w-ci.w;
    float dist = d0*d0 + d1*d1 + d2*d2 + d3*d3;
    float w = __expf(-10.f*dist);
    Ss += w;
    Ts += dist*w;
  }
  Sp[(size_t)c*R_ + rj] = Ss;
  Tp[(size_t)c*R_ + rj] = Ts;
}

// ---------------------------------------------------------------------------
// Kernel 3: GNN layer GEMM + bias + mask + bn + tanh, fused.
// out[r,o] = tanh(g[o]*(( x@A_lo + (m*S-1)*(x@A_hi) + m*T*A_last + b )*m)*INV_S + be[o])
// Block: 256 threads = 32 rows x 64 outs; thread (o = tid&63, jr = tid>>6)
// computes 8 rows for its column o (2 accumulators each).
// KP = padded K (36 for layer 0 / K=33, 64 for layers 1-4).
// ---------------------------------------------------------------------------
template<int KP>
__global__ __launch_bounds__(256) void gnn_gemm(
    const float* __restrict__ xin, const float* __restrict__ A, int K,
    const float* __restrict__ bias, const float* __restrict__ gamma,
    const float* __restrict__ beta,
    const float* __restrict__ Sp, const float* __restrict__ Tp,
    const float* __restrict__ maskb, float* __restrict__ xout)
{
  __shared__ float alo[KP*64];
  __shared__ float ahi[KP*64];
  __shared__ float xl[32*KP];
  int tid = threadIdx.x;
  // stage A (zero-pad rows K..KP-1)
  for (int idx = tid; idx < KP*64; idx += 256){
    int f = idx >> 6;
    alo[idx] = (f < K) ? A[idx] : 0.f;
    ahi[idx] = (f < K) ? A[(size_t)K*64 + idx] : 0.f;
  }
  // stage x tile (32 rows x KP features; global row stride 64)
  int jbase = blockIdx.x*32;
  for (int idx = tid; idx < 32*KP; idx += 256){
    int jj = idx / KP;
    int f  = idx - jj*KP;
    xl[idx] = xin[(size_t)(jbase+jj)*64 + f];
  }
  __syncthreads();
  int o = tid & 63, jr = tid >> 6;
  float acc1[8], acc2[8];
#pragma unroll
  for (int jj=0;jj<8;jj++){ acc1[jj]=0.f; acc2[jj]=0.f; }
  for (int fc = 0; fc < KP; fc += 4){
    float4 xv[8];
#pragma unroll
    for (int jj=0;jj<8;jj++)
      xv[jj] = *(const float4*)&xl[(jr*8+jj)*KP + fc];   // wave-uniform broadcast
#pragma unroll
    for (int u=0;u<4;u++){
      float a1 = alo[(fc+u)*64 + o];
      float a2 = ahi[(fc+u)*64 + o];
#pragma unroll
      for (int jj=0;jj<8;jj++){
        float xu = ((const float*)&xv[jj])[u];
        acc1[jj] = fmaf(xu, a1, acc1[jj]);
        acc2[jj] = fmaf(xu, a2, acc2[jj]);
      }
    }
  }
  float alast = A[(size_t)2*K*64 + o];
  float bo = bias[o], go = gamma[o], be = beta[o];
#pragma unroll
  for (int jj=0;jj<8;jj++){
    int r = jbase + jr*8 + jj;
    float m = maskb[r];
    float Ssum = Sp[r] + Sp[R_+r] + Sp[2*R_+r] + Sp[3*R_+r];
    float Tsum = Tp[r] + Tp[R_+r] + Tp[2*R_+r] + Tp[3*R_+r];
    float sc = m*Ssum - 1.f;
    float tc = m*Tsum;
    float val = (acc1[jj] + sc*acc2[jj] + tc*alast + bo) * m;
    xout[(size_t)r*64 + o] = tanhf(go*(val*INV_S) + be);
  }
}

// ---------------------------------------------------------------------------
// Kernel 4: dense0 split-K partials. X is x5 viewed as (64, 32768) row-major
// (identical memory layout). Each block: k-chunk of 128, all 64 rows x 128
// cols. Thread: 4 rows x 8 cols. Writes partial[blk][r][o].
// ---------------------------------------------------------------------------
__global__ __launch_bounds__(256) void dense0_partial(
    const float* __restrict__ X, const float* __restrict__ W,
    float* __restrict__ partial)
{
  __shared__ float xt[64*32];
  __shared__ float wt[32*128];
  int tid = threadIdx.x;
  int k0 = blockIdx.x*128;
  int og = (tid & 15)*8;
  int rg = (tid >> 4)*4;
  float acc[4][8];
#pragma unroll
  for (int a=0;a<4;a++)
#pragma unroll
    for (int u=0;u<8;u++) acc[a][u]=0.f;
  for (int kt = 0; kt < 128; kt += 32){
    __syncthreads();
    for (int idx = tid; idx < 64*32; idx += 256){
      int r = idx >> 5, k = idx & 31;
      xt[idx] = X[(size_t)r*32768 + k0 + kt + k];
    }
    for (int idx = tid; idx < 32*128; idx += 256){
      wt[idx] = W[(size_t)(k0+kt)*128 + idx];
    }
    __syncthreads();
#pragma unroll 4
    for (int k=0;k<32;k++){
      float4 w0 = *(const float4*)&wt[k*128 + og];
      float4 w1 = *(const float4*)&wt[k*128 + og + 4];
      float xs[4];
#pragma unroll
      for (int rr=0;rr<4;rr++) xs[rr] = xt[(rg+rr)*32 + k];
#pragma unroll
      for (int rr=0;rr<4;rr++){
        acc[rr][0] = fmaf(xs[rr], w0.x, acc[rr][0]);
        acc[rr][1] = fmaf(xs[rr], w0.y, acc[rr][1]);
        acc[rr][2] = fmaf(xs[rr], w0.z, acc[rr][2]);
        acc[rr][3] = fmaf(xs[rr], w0.w, acc[rr][3]);
        acc[rr][4] = fmaf(xs[rr], w1.x, acc[rr][4]);
        acc[rr][5] = fmaf(xs[rr], w1.y, acc[rr][5]);
        acc[rr][6] = fmaf(xs[rr], w1.z, acc[rr][6]);
        acc[rr][7] = fmaf(xs[rr], w1.w, acc[rr][7]);
      }
    }
  }
  float* pb = partial + (size_t)blockIdx.x*8192;
#pragma unroll
  for (int rr=0;rr<4;rr++){
    *(float4*)&pb[(rg+rr)*128 + og]     = *(float4*)&acc[rr][0];
    *(float4*)&pb[(rg+rr)*128 + og + 4] = *(float4*)&acc[rr][4];
  }
}

// ---------------------------------------------------------------------------
// Kernel 5: reduce 256 partials, + bias, bn, sigmoid -> h0 (64x128)
// ---------------------------------------------------------------------------
__global__ __launch_bounds__(256) void dense0_reduce(
    const float* __restrict__ partial, const float* __restrict__ db0,
    const float* __restrict__ dg, const float* __restrict__ dbe,
    float* __restrict__ h0)
{
  int idx = blockIdx.x*256 + threadIdx.x;   // 0..8191
  float s = 0.f;
#pragma unroll 16
  for (int p=0;p<256;p++) s += partial[(size_t)p*8192 + idx];
  int o = idx & 127;
  float v = dg[o]*((s + db0[o])*INV_S) + dbe[o];
  h0[idx] = 1.f/(1.f + __expf(-v));
}

// ---------------------------------------------------------------------------
// Kernel 6: h1 = sigmoid(bn(h0@dW1+db1)); out2 = h1@W2 + b2; emit (64,4).
// One block per batch row b; thread o computes h1[b,o], then LDS reduce.
// ---------------------------------------------------------------------------
__global__ __launch_bounds__(128) void dense_tail(
    const float* __restrict__ h0, const float* __restrict__ dW1,
    const float* __restrict__ db1, const float* __restrict__ dg,
    const float* __restrict__ dbe, const float* __restrict__ W2,
    const float* __restrict__ b2, float* __restrict__ out)
{
  __shared__ float h[128];
  __shared__ float red0[128], red1[128];
  int b = blockIdx.x, o = threadIdx.x;
  h[o] = h0[b*128 + o];
  __syncthreads();
  float acc = 0.f;
#pragma unroll 8
  for (int k=0;k<128;k++) acc = fmaf(h[k], dW1[k*128 + o], acc);
  float v = dg[o]*((acc + db1[o])*INV_S) + dbe[o];
  float h1 = 1.f/(1.f + __expf(-v));
  red0[o] = h1 * W2[o*2+0];
  red1[o] = h1 * W2[o*2+1];
  __syncthreads();
  for (int s=64; s>0; s>>=1){
    if (o < s){ red0[o] += red0[o+s]; red1[o] += red1[o+s]; }
    __syncthreads();
  }
  if (o == 0){
    out[b*4+0] = red0[0] + b2[0];
    out[b*4+1] = red1[0] + b2[1];
    out[b*4+2] = 0.f;
    out[b*4+3] = 0.f;
  }
}

// ---------------------------------------------------------------------------
extern "C" void kernel_launch(void* const* d_in, const int* in_sizes, int n_in,
                              void* d_out, int out_size, void* d_ws, size_t ws_size,
                              hipStream_t stream)
{
  const float* xx   = (const float*)d_in[0];
  const float* emb1 = (const float*)d_in[1];
  const float* emb2 = (const float*)d_in[2];
  const float* emb3 = (const float*)d_in[3];
  const float* A0   = (const float*)d_in[4];
  const float* b0   = (const float*)d_in[5];
  const float* Ar   = (const float*)d_in[6];   // (4,129,64)
  const float* br   = (const float*)d_in[7];   // (4,64)
  const float* bng  = (const float*)d_in[8];   // (5,64)
  const float* bnb  = (const float*)d_in[9];   // (5,64)
  const float* dW0  = (const float*)d_in[10];  // (32768,128)
  const float* db0  = (const float*)d_in[11];
  const float* dW1  = (const float*)d_in[12];  // (128,128)
  const float* db1  = (const float*)d_in[13];
  const float* dbg  = (const float*)d_in[14];  // (2,128)
  const float* dbb  = (const float*)d_in[15];
  const float* W2   = (const float*)d_in[16];  // (128,2)
  const float* b2   = (const float*)d_in[17];

  float* ws = (float*)d_ws;
  float* xA      = ws;                               // 32768*64
  float* xB      = xA + (size_t)R_*64;               // 32768*64
  float* Sp      = xB + (size_t)R_*64;               // 4*32768
  float* Tp      = Sp + (size_t)R_*4;                // 4*32768
  float* maskb   = Tp + (size_t)R_*4;                // 32768
  float* partial = maskb + R_;                       // 256*8192
  float* h0      = partial + (size_t)256*8192;       // 8192

  build_x0<<<R_/256, 256, 0, stream>>>(xx, emb1, emb2, emb3, xA, maskb);

  // layer 0: coords = x0 channels 31,32 (ndim=2), K=33 padded to 36
  dist_partial<<<dim3(N_/64, 4, B_), 64, 0, stream>>>(xA, 31, 2, Sp, Tp);
  gnn_gemm<36><<<R_/32, 256, 0, stream>>>(xA, A0, 33, b0, bng, bnb, Sp, Tp, maskb, xB);

  // layers 1..4: coords = channels 60..63 (ndim=4), K=64
  float* bufs[2] = {xA, xB};
  int curi = 1;
  for (int k=0;k<4;k++){
    const float* cur = bufs[curi];
    float* nxt = bufs[1-curi];
    dist_partial<<<dim3(N_/64, 4, B_), 64, 0, stream>>>(cur, 60, 4, Sp, Tp);
    gnn_gemm<64><<<R_/32, 256, 0, stream>>>(cur, Ar + (size_t)k*129*64, 64,
        br + k*64, bng + (k+1)*64, bnb + (k+1)*64, Sp, Tp, maskb, nxt);
    curi ^= 1;
  }
  const float* x5 = bufs[curi];   // ends at xB

  dense0_partial<<<256, 256, 0, stream>>>(x5, dW0, partial);
  dense0_reduce<<<8192/256, 256, 0, stream>>>(partial, db0, dbg, dbb, h0);
  dense_tail<<<B_, 128, 0, stream>>>(h0, dW1, db1, dbg + 128, dbb + 128,
                                     W2, b2, (float*)d_out);
}

// Round 2
// 279.729 us; speedup vs baseline: 1.8141x; 1.8141x over previous
//
#include <hip/hip_runtime.h>
#include <math.h>

#define B_ 64
#define N_ 512
#define NOUT_ 64
#define R_ (B_*N_)            // 32768 rows total
#define INV_S 0.9995003746877732f   // 1/sqrt(1+1e-3)

// ---------------------------------------------------------------------------
// Kernel 1: embeddings + assemble x0 (33 features, padded to 36 with zeros,
// stored with row stride 64), extract mask.
// ---------------------------------------------------------------------------
__global__ __launch_bounds__(256) void build_x0(
    const float* __restrict__ xx, const float* __restrict__ emb1,
    const float* __restrict__ emb2, const float* __restrict__ emb3,
    float* __restrict__ x0, float* __restrict__ maskb)
{
  int r = blockIdx.x*256 + threadIdx.x;   // 0..32767
  const float* row = xx + (size_t)r*30;
  float v[30];
#pragma unroll
  for (int i=0;i<30;i++) v[i] = row[i];
  int i1 = (int)fabsf(v[27]);
  int i2 = (int)fabsf(v[28]);
  int i3 = (int)fabsf(v[29]);
  float* o = x0 + (size_t)r*64;
  o[0]=emb1[i1*2+0]; o[1]=emb1[i1*2+1];
  o[2]=emb2[i2*2+0]; o[3]=emb2[i2*2+1];
  o[4]=emb3[i3*2+0]; o[5]=emb3[i3*2+1];
#pragma unroll
  for (int i=0;i<27;i++) o[6+i] = v[i];
  o[33]=0.f; o[34]=0.f; o[35]=0.f;       // pad so K=33 GEMM can run K=36
  maskb[r] = v[0];
}

// ---------------------------------------------------------------------------
// Kernel 2: pairwise-distance partial sums. 256-thread blocks.
// grid (N/256, 4 i-chunks, B). Block (jx,c,b): for its 256 j's, sums
// w=exp(-10*dist) and dist*w over i in [c*128, c*128+128).
// ---------------------------------------------------------------------------
__global__ __launch_bounds__(256) void dist_partial(
    const float* __restrict__ xbuf, int coff, int ndim,
    float* __restrict__ Sp, float* __restrict__ Tp)
{
  __shared__ float4 cl[128];
  int jx = blockIdx.x, c = blockIdx.y, b = blockIdx.z;
  int tid = threadIdx.x;
  if (tid < 128){
    int r = b*N_ + c*128 + tid;
    float4 cv;
    cv.x = xbuf[(size_t)r*64 + coff + 0];
    cv.y = xbuf[(size_t)r*64 + coff + 1];
    cv.z = (ndim > 2) ? xbuf[(size_t)r*64 + coff + 2] : 0.f;
    cv.w = (ndim > 2) ? xbuf[(size_t)r*64 + coff + 3] : 0.f;
    cl[tid] = cv;
  }
  __syncthreads();
  int rj = b*N_ + jx*256 + tid;
  float4 cj;
  cj.x = xbuf[(size_t)rj*64 + coff + 0];
  cj.y = xbuf[(size_t)rj*64 + coff + 1];
  cj.z = (ndim > 2) ? xbuf[(size_t)rj*64 + coff + 2] : 0.f;
  cj.w = (ndim > 2) ? xbuf[(size_t)rj*64 + coff + 3] : 0.f;
  float Ss = 0.f, Ts = 0.f;
#pragma unroll 4
  for (int i=0;i<128;i++){
    float4 ci = cl[i];
    float d0 = cj.x-ci.x, d1 = cj.y-ci.y, d2 = cj.z-ci.z, d3 = cj.w-ci.w;
    float dist = d0*d0 + d1*d1 + d2*d2 + d3*d3;
    float w = __expf(-10.f*dist);
    Ss += w;
    Ts += dist*w;
  }
  Sp[(size_t)c*R_ + rj] = Ss;
  Tp[(size_t)c*R_ + rj] = Ts;
}

// ---------------------------------------------------------------------------
// Kernel 3: GNN layer GEMM + bias + mask + bn + tanh, fused.
// Block: 256 threads = 64 rows x 64 outs; thread (og=tid&15 -> 4 outs,
// rg=tid>>4 -> 4 rows). All LDS traffic is ds_read_b128:
//  per 4-k chunk: 8 A reads (2 mats x 4 k) + 4 x reads -> 128 FMAs.
// XS = padded x row stride chosen so the 4 row-group addresses of an x read
// land on <=2 distinct banks (2-way conflict is free).
// __launch_bounds__(256,4) caps VGPRs at 128 (round-1 spilled at 256).
// ---------------------------------------------------------------------------
template<int KP, int XS>
__global__ __launch_bounds__(256, 4) void gnn_gemm(
    const float* __restrict__ xin, const float* __restrict__ A, int K,
    const float* __restrict__ bias, const float* __restrict__ gamma,
    const float* __restrict__ beta,
    const float* __restrict__ Sp, const float* __restrict__ Tp,
    const float* __restrict__ maskb, float* __restrict__ xout)
{
  __shared__ float alo[KP*64];
  __shared__ float ahi[KP*64];
  __shared__ float xl[64*XS];
  __shared__ float scl[64], tcl[64], ml[64];
  int tid = threadIdx.x;
  int jbase = blockIdx.x*64;

  // stage A (zero-pad rows K..KP-1)
  for (int idx = tid; idx < KP*64; idx += 256){
    int f = idx >> 6;
    alo[idx] = (f < K) ? A[idx] : 0.f;
    ahi[idx] = (f < K) ? A[(size_t)K*64 + idx] : 0.f;
  }
  // stage x tile (64 rows x KP feats, global row stride 64, LDS stride XS)
  if constexpr (KP == 64){
    for (int idx = tid; idx < 64*16; idx += 256){
      int jj = idx >> 4, fq = idx & 15;
      *(float4*)&xl[jj*XS + fq*4] =
          *(const float4*)&xin[(size_t)(jbase+jj)*64 + fq*4];
    }
  } else {
    for (int idx = tid; idx < 64*KP; idx += 256){
      int jj = idx / KP, f = idx - jj*KP;
      xl[jj*XS + f] = xin[(size_t)(jbase+jj)*64 + f];
    }
  }
  // per-row scalars: sc = m*S-1, tc = m*T
  if (tid < 64){
    int r = jbase + tid;
    float m = maskb[r];
    float Ssum = Sp[r] + Sp[R_+r] + Sp[2*R_+r] + Sp[3*R_+r];
    float Tsum = Tp[r] + Tp[R_+r] + Tp[2*R_+r] + Tp[3*R_+r];
    scl[tid] = m*Ssum - 1.f;
    tcl[tid] = m*Tsum;
    ml[tid]  = m;
  }
  __syncthreads();

  int og = tid & 15, rg = tid >> 4;
  int o0 = og*4, r0 = rg*4;
  float4 acc1[4], acc2[4];
#pragma unroll
  for (int rr=0;rr<4;rr++){
    acc1[rr] = make_float4(0.f,0.f,0.f,0.f);
    acc2[rr] = make_float4(0.f,0.f,0.f,0.f);
  }
#pragma unroll 1
  for (int kc = 0; kc < KP; kc += 4){
    float4 a1[4], a2[4], xv[4];
#pragma unroll
    for (int u=0;u<4;u++){
      a1[u] = *(const float4*)&alo[(kc+u)*64 + o0];
      a2[u] = *(const float4*)&ahi[(kc+u)*64 + o0];
    }
#pragma unroll
    for (int rr=0;rr<4;rr++)
      xv[rr] = *(const float4*)&xl[(r0+rr)*XS + kc];
#pragma unroll
    for (int u=0;u<4;u++){
#pragma unroll
      for (int rr=0;rr<4;rr++){
        float xu = ((const float*)&xv[rr])[u];
        acc1[rr].x = fmaf(xu, a1[u].x, acc1[rr].x);
        acc1[rr].y = fmaf(xu, a1[u].y, acc1[rr].y);
        acc1[rr].z = fmaf(xu, a1[u].z, acc1[rr].z);
        acc1[rr].w = fmaf(xu, a1[u].w, acc1[rr].w);
        acc2[rr].x = fmaf(xu, a2[u].x, acc2[rr].x);
        acc2[rr].y = fmaf(xu, a2[u].y, acc2[rr].y);
        acc2[rr].z = fmaf(xu, a2[u].z, acc2[rr].z);
        acc2[rr].w = fmaf(xu, a2[u].w, acc2[rr].w);
      }
    }
  }

  float4 alast = *(const float4*)&A[(size_t)2*K*64 + o0];
  float4 bo = *(const float4*)&bias[o0];
  float4 go = *(const float4*)&gamma[o0];
  float4 be = *(const float4*)&beta[o0];
#pragma unroll
  for (int rr=0;rr<4;rr++){
    int r = jbase + r0 + rr;
    float sc = scl[r0+rr], tc = tcl[r0+rr], m = ml[r0+rr];
    float4 v;
    v.x = (acc1[rr].x + sc*acc2[rr].x + tc*alast.x + bo.x)*m;
    v.y = (acc1[rr].y + sc*acc2[rr].y + tc*alast.y + bo.y)*m;
    v.z = (acc1[rr].z + sc*acc2[rr].z + tc*alast.z + bo.z)*m;
    v.w = (acc1[rr].w + sc*acc2[rr].w + tc*alast.w + bo.w)*m;
    float4 t;
    t.x = tanhf(go.x*(v.x*INV_S) + be.x);
    t.y = tanhf(go.y*(v.y*INV_S) + be.y);
    t.z = tanhf(go.z*(v.z*INV_S) + be.z);
    t.w = tanhf(go.w*(v.w*INV_S) + be.w);
    *(float4*)&xout[(size_t)r*64 + o0] = t;
  }
}

// ---------------------------------------------------------------------------
// Kernel 4: dense0 split-K partials. X viewed as (64, 32768) row-major.
// Each block: k-chunk of 128, all 64 rows x 128 cols. Thread: 4 rows x 8
// cols. Writes partial[blk][r][o].
// ---------------------------------------------------------------------------
__global__ __launch_bounds__(256) void dense0_partial(
    const float* __restrict__ X, const float* __restrict__ W,
    float* __restrict__ partial)
{
  __shared__ float xt[64*32];
  __shared__ float wt[32*128];
  int tid = threadIdx.x;
  int k0 = blockIdx.x*128;
  int og = (tid & 15)*8;
  int rg = (tid >> 4)*4;
  float acc[4][8];
#pragma unroll
  for (int a=0;a<4;a++)
#pragma unroll
    for (int u=0;u<8;u++) acc[a][u]=0.f;
  for (int kt = 0; kt < 128; kt += 32){
    __syncthreads();
    for (int idx = tid; idx < 64*32; idx += 256){
      int r = idx >> 5, k = idx & 31;
      xt[idx] = X[(size_t)r*32768 + k0 + kt + k];
    }
    for (int idx = tid; idx < 32*128; idx += 256){
      wt[idx] = W[(size_t)(k0+kt)*128 + idx];
    }
    __syncthreads();
#pragma unroll 4
    for (int k=0;k<32;k++){
      float4 w0 = *(const float4*)&wt[k*128 + og];
      float4 w1 = *(const float4*)&wt[k*128 + og + 4];
      float xs[4];
#pragma unroll
      for (int rr=0;rr<4;rr++) xs[rr] = xt[(rg+rr)*32 + k];
#pragma unroll
      for (int rr=0;rr<4;rr++){
        acc[rr][0] = fmaf(xs[rr], w0.x, acc[rr][0]);
        acc[rr][1] = fmaf(xs[rr], w0.y, acc[rr][1]);
        acc[rr][2] = fmaf(xs[rr], w0.z, acc[rr][2]);
        acc[rr][3] = fmaf(xs[rr], w0.w, acc[rr][3]);
        acc[rr][4] = fmaf(xs[rr], w1.x, acc[rr][4]);
        acc[rr][5] = fmaf(xs[rr], w1.y, acc[rr][5]);
        acc[rr][6] = fmaf(xs[rr], w1.z, acc[rr][6]);
        acc[rr][7] = fmaf(xs[rr], w1.w, acc[rr][7]);
      }
    }
  }
  float* pb = partial + (size_t)blockIdx.x*8192;
#pragma unroll
  for (int rr=0;rr<4;rr++){
    *(float4*)&pb[(rg+rr)*128 + og]     = *(float4*)&acc[rr][0];
    *(float4*)&pb[(rg+rr)*128 + og + 4] = *(float4*)&acc[rr][4];
  }
}

// ---------------------------------------------------------------------------
// Kernel 5: reduce 256 partials, + bias, bn, sigmoid -> h0 (64x128)
// ---------------------------------------------------------------------------
__global__ __launch_bounds__(256) void dense0_reduce(
    const float* __restrict__ partial, const float* __restrict__ db0,
    const float* __restrict__ dg, const float* __restrict__ dbe,
    float* __restrict__ h0)
{
  int idx = blockIdx.x*256 + threadIdx.x;   // 0..8191
  float s = 0.f;
#pragma unroll 16
  for (int p=0;p<256;p++) s += partial[(size_t)p*8192 + idx];
  int o = idx & 127;
  float v = dg[o]*((s + db0[o])*INV_S) + dbe[o];
  h0[idx] = 1.f/(1.f + __expf(-v));
}

// ---------------------------------------------------------------------------
// Kernel 6: h1 = sigmoid(bn(h0@dW1+db1)); out2 = h1@W2 + b2; emit (64,4).
// ---------------------------------------------------------------------------
__global__ __launch_bounds__(128) void dense_tail(
    const float* __restrict__ h0, const float* __restrict__ dW1,
    const float* __restrict__ db1, const float* __restrict__ dg,
    const float* __restrict__ dbe, const float* __restrict__ W2,
    const float* __restrict__ b2, float* __restrict__ out)
{
  __shared__ float h[128];
  __shared__ float red0[128], red1[128];
  int b = blockIdx.x, o = threadIdx.x;
  h[o] = h0[b*128 + o];
  __syncthreads();
  float acc = 0.f;
#pragma unroll 8
  for (int k=0;k<128;k++) acc = fmaf(h[k], dW1[k*128 + o], acc);
  float v = dg[o]*((acc + db1[o])*INV_S) + dbe[o];
  float h1 = 1.f/(1.f + __expf(-v));
  red0[o] = h1 * W2[o*2+0];
  red1[o] = h1 * W2[o*2+1];
  __syncthreads();
  for (int s=64; s>0; s>>=1){
    if (o < s){ red0[o] += red0[o+s]; red1[o] += red1[o+s]; }
    __syncthreads();
  }
  if (o == 0){
    out[b*4+0] = red0[0] + b2[0];
    out[b*4+1] = red1[0] + b2[1];
    out[b*4+2] = 0.f;
    out[b*4+3] = 0.f;
  }
}

// ---------------------------------------------------------------------------
extern "C" void kernel_launch(void* const* d_in, const int* in_sizes, int n_in,
                              void* d_out, int out_size, void* d_ws, size_t ws_size,
                              hipStream_t stream)
{
  const float* xx   = (const float*)d_in[0];
  const float* emb1 = (const float*)d_in[1];
  const float* emb2 = (const float*)d_in[2];
  const float* emb3 = (const float*)d_in[3];
  const float* A0   = (const float*)d_in[4];
  const float* b0   = (const float*)d_in[5];
  const float* Ar   = (const float*)d_in[6];   // (4,129,64)
  const float* br   = (const float*)d_in[7];   // (4,64)
  const float* bng  = (const float*)d_in[8];   // (5,64)
  const float* bnb  = (const float*)d_in[9];   // (5,64)
  const float* dW0  = (const float*)d_in[10];  // (32768,128)
  const float* db0  = (const float*)d_in[11];
  const float* dW1  = (const float*)d_in[12];  // (128,128)
  const float* db1  = (const float*)d_in[13];
  const float* dbg  = (const float*)d_in[14];  // (2,128)
  const float* dbb  = (const float*)d_in[15];
  const float* W2   = (const float*)d_in[16];  // (128,2)
  const float* b2   = (const float*)d_in[17];

  float* ws = (float*)d_ws;
  float* xA      = ws;                               // 32768*64
  float* xB      = xA + (size_t)R_*64;               // 32768*64
  float* Sp      = xB + (size_t)R_*64;               // 4*32768
  float* Tp      = Sp + (size_t)R_*4;                // 4*32768
  float* maskb   = Tp + (size_t)R_*4;                // 32768
  float* partial = maskb + R_;                       // 256*8192
  float* h0      = partial + (size_t)256*8192;       // 8192

  build_x0<<<R_/256, 256, 0, stream>>>(xx, emb1, emb2, emb3, xA, maskb);

  // layer 0: coords = x0 channels 31,32 (ndim=2), K=33 padded to 36
  dist_partial<<<dim3(N_/256, 4, B_), 256, 0, stream>>>(xA, 31, 2, Sp, Tp);
  gnn_gemm<36,44><<<R_/64, 256, 0, stream>>>(xA, A0, 33, b0, bng, bnb, Sp, Tp, maskb, xB);

  // layers 1..4: coords = channels 60..63 (ndim=4), K=64
  float* bufs[2] = {xA, xB};
  int curi = 1;
  for (int k=0;k<4;k++){
    const float* cur = bufs[curi];
    float* nxt = bufs[1-curi];
    dist_partial<<<dim3(N_/256, 4, B_), 256, 0, stream>>>(cur, 60, 4, Sp, Tp);
    gnn_gemm<64,68><<<R_/64, 256, 0, stream>>>(cur, Ar + (size_t)k*129*64, 64,
        br + k*64, bng + (k+1)*64, bnb + (k+1)*64, Sp, Tp, maskb, nxt);
    curi ^= 1;
  }
  const float* x5 = bufs[curi];   // ends at xB

  dense0_partial<<<256, 256, 0, stream>>>(x5, dW0, partial);
  dense0_reduce<<<8192/256, 256, 0, stream>>>(partial, db0, dbg, dbb, h0);
  dense_tail<<<B_, 128, 0, stream>>>(h0, dW1, db1, dbg + 128, dbb + 128,
                                     W2, b2, (float*)d_out);
}

// Round 3
// 246.595 us; speedup vs baseline: 2.0579x; 1.1344x over previous
//
#include <hip/hip_runtime.h>
#include <math.h>

#define B_ 64
#define N_ 512
#define NOUT_ 64
#define R_ (B_*N_)            // 32768 rows total
#define INV_S 0.9995003746877732f   // 1/sqrt(1+1e-3)

// ---------------------------------------------------------------------------
// Fused GNN layer: per-block = (j-chunk of 64 rows) x (batch b).
//  Phase A: stage all 512 coords of batch b (float4, zeros for ndim=2),
//           stage A weights (lo/hi), stage x tile (64 x KP, stride XS),
//           per-row mask from xx.
//  Phase B: S,T for the 64 j's: 4 waves each sum a 128-wide i-range
//           (wave-uniform LDS broadcasts), combine -> scl/tcl.
//  Phase C: 64x64 GEMM tile (thread = 4 rows x 4 outs x 2 mats, all
//           ds_read_b128) + alast/bias/mask/bn/tanh epilogue.
// LAYER0: x tile built in-kernel from xx + embeddings (K=33 pad 36);
//         coords = xx ch 25,26. Else: x from xin, coords = ch 60..63.
// ---------------------------------------------------------------------------
template<int KP, int XS, int LAYER0>
__global__ __launch_bounds__(256, 4) void gnn_layer(
    const float* __restrict__ xx, const float* __restrict__ xin,
    const float* __restrict__ A, int K,
    const float* __restrict__ bias, const float* __restrict__ gamma,
    const float* __restrict__ beta,
    const float* __restrict__ emb1, const float* __restrict__ emb2,
    const float* __restrict__ emb3, float* __restrict__ xout)
{
  __shared__ float4 cl[512];
  __shared__ float alo[KP*64];
  __shared__ float ahi[KP*64];
  __shared__ float xl[64*XS];
  __shared__ float spart[256], tpart[256];
  __shared__ float scl[64], tcl[64], ml[64];

  int tid = threadIdx.x;
  int jc = blockIdx.x;            // 0..7
  int b  = blockIdx.y;            // 0..63
  int rbase = b*N_;
  int jloc  = jc*64;

  // ---- stage coords for all 512 rows of this batch ----
  if constexpr (LAYER0){
    for (int i = tid; i < 512; i += 256){
      const float* row = xx + (size_t)(rbase+i)*30;
      cl[i] = make_float4(row[25], row[26], 0.f, 0.f);
    }
  } else {
    for (int i = tid; i < 512; i += 256){
      cl[i] = *(const float4*)&xin[(size_t)(rbase+i)*64 + 60];
    }
  }

  // ---- stage A (lo/hi), zero-pad rows K..KP-1 ----
  if constexpr (KP == 64){
    const float4* A4 = (const float4*)A;
    float4* alo4 = (float4*)alo;
    float4* ahi4 = (float4*)ahi;
    for (int idx = tid; idx < 1024; idx += 256){
      alo4[idx] = A4[idx];
      ahi4[idx] = A4[1024 + idx];
    }
  } else {
    for (int idx = tid; idx < KP*64; idx += 256){
      int f = idx >> 6;
      alo[idx] = (f < K) ? A[idx] : 0.f;
      ahi[idx] = (f < K) ? A[(size_t)K*64 + idx] : 0.f;
    }
  }

  // ---- stage x tile (64 rows x KP) + mask ----
  if constexpr (LAYER0){
    if (tid < 64){
      int r = rbase + jloc + tid;
      const float* row = xx + (size_t)r*30;
      float v[30];
#pragma unroll
      for (int i=0;i<30;i++) v[i] = row[i];
      int i1 = (int)fabsf(v[27]);
      int i2 = (int)fabsf(v[28]);
      int i3 = (int)fabsf(v[29]);
      float* o = &xl[tid*XS];
      o[0]=emb1[i1*2+0]; o[1]=emb1[i1*2+1];
      o[2]=emb2[i2*2+0]; o[3]=emb2[i2*2+1];
      o[4]=emb3[i3*2+0]; o[5]=emb3[i3*2+1];
#pragma unroll
      for (int i=0;i<27;i++) o[6+i] = v[i];
      o[33]=0.f; o[34]=0.f; o[35]=0.f;
      ml[tid] = v[0];
    }
  } else {
    for (int idx = tid; idx < 1024; idx += 256){
      int jj = idx >> 4, fq = idx & 15;
      *(float4*)&xl[jj*XS + fq*4] =
          *(const float4*)&xin[(size_t)(rbase+jloc+jj)*64 + fq*4];
    }
    if (tid < 64) ml[tid] = xx[(size_t)(rbase+jloc+tid)*30];
  }
  __syncthreads();

  // ---- S,T: wave q sums i in [q*128, q*128+128) for j = tid&63 ----
  {
    int jj = tid & 63, q = tid >> 6;
    float4 cj = cl[jloc + jj];
    float Ss = 0.f, Ts = 0.f;
    int base = q*128;
#pragma unroll 8
    for (int i=0;i<128;i++){
      float4 ci = cl[base+i];
      float d0 = cj.x-ci.x, d1 = cj.y-ci.y, d2 = cj.z-ci.z, d3 = cj.w-ci.w;
      float dist = d0*d0 + d1*d1 + d2*d2 + d3*d3;
      float w = __expf(-10.f*dist);
      Ss += w;
      Ts += dist*w;
    }
    spart[tid] = Ss;
    tpart[tid] = Ts;
  }
  __syncthreads();
  if (tid < 64){
    float S = spart[tid] + spart[tid+64] + spart[tid+128] + spart[tid+192];
    float T = tpart[tid] + tpart[tid+64] + tpart[tid+128] + tpart[tid+192];
    float m = ml[tid];
    scl[tid] = m*S - 1.f;
    tcl[tid] = m*T;
  }
  __syncthreads();

  // ---- GEMM tile: thread = 4 rows x 4 outs, two matrices ----
  int o0 = (tid & 15)*4, r0 = (tid >> 4)*4;
  float4 acc1[4], acc2[4];
#pragma unroll
  for (int rr=0;rr<4;rr++){
    acc1[rr] = make_float4(0.f,0.f,0.f,0.f);
    acc2[rr] = make_float4(0.f,0.f,0.f,0.f);
  }
#pragma unroll 1
  for (int kc = 0; kc < KP; kc += 4){
    float4 a1[4], a2[4], xv[4];
#pragma unroll
    for (int u=0;u<4;u++){
      a1[u] = *(const float4*)&alo[(kc+u)*64 + o0];
      a2[u] = *(const float4*)&ahi[(kc+u)*64 + o0];
    }
#pragma unroll
    for (int rr=0;rr<4;rr++)
      xv[rr] = *(const float4*)&xl[(r0+rr)*XS + kc];
#pragma unroll
    for (int u=0;u<4;u++){
#pragma unroll
      for (int rr=0;rr<4;rr++){
        float xu = ((const float*)&xv[rr])[u];
        acc1[rr].x = fmaf(xu, a1[u].x, acc1[rr].x);
        acc1[rr].y = fmaf(xu, a1[u].y, acc1[rr].y);
        acc1[rr].z = fmaf(xu, a1[u].z, acc1[rr].z);
        acc1[rr].w = fmaf(xu, a1[u].w, acc1[rr].w);
        acc2[rr].x = fmaf(xu, a2[u].x, acc2[rr].x);
        acc2[rr].y = fmaf(xu, a2[u].y, acc2[rr].y);
        acc2[rr].z = fmaf(xu, a2[u].z, acc2[rr].z);
        acc2[rr].w = fmaf(xu, a2[u].w, acc2[rr].w);
      }
    }
  }

  float4 alast = *(const float4*)&A[(size_t)2*K*64 + o0];
  float4 bo = *(const float4*)&bias[o0];
  float4 go = *(const float4*)&gamma[o0];
  float4 be = *(const float4*)&beta[o0];
#pragma unroll
  for (int rr=0;rr<4;rr++){
    int r = rbase + jloc + r0 + rr;
    float sc = scl[r0+rr], tc = tcl[r0+rr], m = ml[r0+rr];
    float4 v;
    v.x = (acc1[rr].x + sc*acc2[rr].x + tc*alast.x + bo.x)*m;
    v.y = (acc1[rr].y + sc*acc2[rr].y + tc*alast.y + bo.y)*m;
    v.z = (acc1[rr].z + sc*acc2[rr].z + tc*alast.z + bo.z)*m;
    v.w = (acc1[rr].w + sc*acc2[rr].w + tc*alast.w + bo.w)*m;
    float4 t;
    t.x = tanhf(go.x*(v.x*INV_S) + be.x);
    t.y = tanhf(go.y*(v.y*INV_S) + be.y);
    t.z = tanhf(go.z*(v.z*INV_S) + be.z);
    t.w = tanhf(go.w*(v.w*INV_S) + be.w);
    *(float4*)&xout[(size_t)r*64 + o0] = t;
  }
}

// ---------------------------------------------------------------------------
// dense0 split-K partials. X viewed as (64, 32768) row-major. Block =
// k-chunk of 128, all 64 rows x 128 cols. Thread: 4 rows x 8 cols.
// ---------------------------------------------------------------------------
__global__ __launch_bounds__(256) void dense0_partial(
    const float* __restrict__ X, const float* __restrict__ W,
    float* __restrict__ partial)
{
  __shared__ float xt[64*32];
  __shared__ float wt[32*128];
  int tid = threadIdx.x;
  int k0 = blockIdx.x*128;
  int og = (tid & 15)*8;
  int rg = (tid >> 4)*4;
  float acc[4][8];
#pragma unroll
  for (int a=0;a<4;a++)
#pragma unroll
    for (int u=0;u<8;u++) acc[a][u]=0.f;
  for (int kt = 0; kt < 128; kt += 32){
    __syncthreads();
    for (int idx = tid; idx < 512; idx += 256){
      int r = idx >> 3, kq = idx & 7;
      *(float4*)&xt[r*32 + kq*4] =
          *(const float4*)&X[(size_t)r*32768 + k0 + kt + kq*4];
    }
    {
      const float4* Wc = (const float4*)&W[(size_t)(k0+kt)*128];
      float4* wt4 = (float4*)wt;
      for (int idx = tid; idx < 1024; idx += 256) wt4[idx] = Wc[idx];
    }
    __syncthreads();
#pragma unroll 4
    for (int k=0;k<32;k++){
      float4 w0 = *(const float4*)&wt[k*128 + og];
      float4 w1 = *(const float4*)&wt[k*128 + og + 4];
      float xs[4];
#pragma unroll
      for (int rr=0;rr<4;rr++) xs[rr] = xt[(rg+rr)*32 + k];
#pragma unroll
      for (int rr=0;rr<4;rr++){
        acc[rr][0] = fmaf(xs[rr], w0.x, acc[rr][0]);
        acc[rr][1] = fmaf(xs[rr], w0.y, acc[rr][1]);
        acc[rr][2] = fmaf(xs[rr], w0.z, acc[rr][2]);
        acc[rr][3] = fmaf(xs[rr], w0.w, acc[rr][3]);
        acc[rr][4] = fmaf(xs[rr], w1.x, acc[rr][4]);
        acc[rr][5] = fmaf(xs[rr], w1.y, acc[rr][5]);
        acc[rr][6] = fmaf(xs[rr], w1.z, acc[rr][6]);
        acc[rr][7] = fmaf(xs[rr], w1.w, acc[rr][7]);
      }
    }
  }
  float* pb = partial + (size_t)blockIdx.x*8192;
#pragma unroll
  for (int rr=0;rr<4;rr++){
    *(float4*)&pb[(rg+rr)*128 + og]     = *(float4*)&acc[rr][0];
    *(float4*)&pb[(rg+rr)*128 + og + 4] = *(float4*)&acc[rr][4];
  }
}

// ---------------------------------------------------------------------------
// Head: reduce 256 partials -> bn+sigmoid -> h0; h1 = sigmoid(bn(h0@dW1));
// out = h1@W2 + b2. One block per batch row, 256 threads (2-way split of
// the partial sum), GEMV + tree-reduce on 128 threads.
// ---------------------------------------------------------------------------
__global__ __launch_bounds__(256) void dense_head(
    const float* __restrict__ partial,
    const float* __restrict__ db0, const float* __restrict__ dg0,
    const float* __restrict__ dbb0,
    const float* __restrict__ dW1, const float* __restrict__ db1,
    const float* __restrict__ dg1, const float* __restrict__ dbb1,
    const float* __restrict__ W2, const float* __restrict__ b2,
    float* __restrict__ out)
{
  __shared__ float sred[256];
  __shared__ float h[128];
  __shared__ float red0[128], red1[128];
  int tid = threadIdx.x;
  int b = blockIdx.x;
  int o = tid & 127, ph = tid >> 7;
  float s = 0.f;
#pragma unroll 16
  for (int p = ph*128; p < ph*128+128; p++)
    s += partial[(size_t)p*8192 + b*128 + o];
  sred[tid] = s;
  __syncthreads();
  if (tid < 128){
    float sum = sred[tid] + sred[tid+128];
    float v = dg0[tid]*((sum + db0[tid])*INV_S) + dbb0[tid];
    h[tid] = 1.f/(1.f + __expf(-v));
  }
  __syncthreads();
  if (tid < 128){
    float acc = 0.f;
#pragma unroll 8
    for (int k=0;k<128;k++) acc = fmaf(h[k], dW1[k*128 + tid], acc);
    float v = dg1[tid]*((acc + db1[tid])*INV_S) + dbb1[tid];
    float h1 = 1.f/(1.f + __expf(-v));
    red0[tid] = h1 * W2[tid*2+0];
    red1[tid] = h1 * W2[tid*2+1];
  }
  __syncthreads();
  for (int st=64; st>0; st>>=1){
    if (tid < st){ red0[tid] += red0[tid+st]; red1[tid] += red1[tid+st]; }
    __syncthreads();
  }
  if (tid == 0){
    out[b*4+0] = red0[0] + b2[0];
    out[b*4+1] = red1[0] + b2[1];
    out[b*4+2] = 0.f;
    out[b*4+3] = 0.f;
  }
}

// ---------------------------------------------------------------------------
extern "C" void kernel_launch(void* const* d_in, const int* in_sizes, int n_in,
                              void* d_out, int out_size, void* d_ws, size_t ws_size,
                              hipStream_t stream)
{
  const float* xx   = (const float*)d_in[0];
  const float* emb1 = (const float*)d_in[1];
  const float* emb2 = (const float*)d_in[2];
  const float* emb3 = (const float*)d_in[3];
  const float* A0   = (const float*)d_in[4];
  const float* b0   = (const float*)d_in[5];
  const float* Ar   = (const float*)d_in[6];   // (4,129,64)
  const float* br   = (const float*)d_in[7];   // (4,64)
  const float* bng  = (const float*)d_in[8];   // (5,64)
  const float* bnb  = (const float*)d_in[9];   // (5,64)
  const float* dW0  = (const float*)d_in[10];  // (32768,128)
  const float* db0  = (const float*)d_in[11];
  const float* dW1  = (const float*)d_in[12];  // (128,128)
  const float* db1  = (const float*)d_in[13];
  const float* dbg  = (const float*)d_in[14];  // (2,128)
  const float* dbb  = (const float*)d_in[15];
  const float* W2   = (const float*)d_in[16];  // (128,2)
  const float* b2   = (const float*)d_in[17];

  float* ws = (float*)d_ws;
  float* xA      = ws;                               // 32768*64
  float* xB      = xA + (size_t)R_*64;               // 32768*64
  float* partial = xB + (size_t)R_*64;               // 256*8192

  dim3 lgrid(8, 64);
  // layer 0: out -> xA
  gnn_layer<36,44,1><<<lgrid, 256, 0, stream>>>(
      xx, nullptr, A0, 33, b0, bng, bnb, emb1, emb2, emb3, xA);
  // layers 1..4: ping-pong xA <-> xB; x5 ends in xA
  float* bufs[2] = {xA, xB};
  int curi = 0;
  for (int k=0;k<4;k++){
    const float* cur = bufs[curi];
    float* nxt = bufs[1-curi];
    gnn_layer<64,68,0><<<lgrid, 256, 0, stream>>>(
        xx, cur, Ar + (size_t)k*129*64, 64, br + k*64,
        bng + (k+1)*64, bnb + (k+1)*64, emb1, emb2, emb3, nxt);
    curi ^= 1;
  }
  const float* x5 = bufs[curi];   // xA

  dense0_partial<<<256, 256, 0, stream>>>(x5, dW0, partial);
  dense_head<<<B_, 256, 0, stream>>>(partial, db0, dbg, dbb,
                                     dW1, db1, dbg + 128, dbb + 128,
                                     W2, b2, (float*)d_out);
}